// Round 10
// baseline (240.303 us; speedup 1.0000x reference)
//
#include <hip/hip_runtime.h>
#include <hip/hip_bf16.h>

// Problem constants (B=2, S=2048, D=1024, H=16, DK=DV=64)
#define H_    16
#define S_    2048
#define D_    1024
#define MAXV  1e10f

typedef __attribute__((ext_vector_type(8))) short short8;
typedef __attribute__((ext_vector_type(4))) float f32x4;

__device__ __forceinline__ unsigned short f2bf(float f) {
    union { float f; unsigned u; } x; x.f = f;
    unsigned r = x.u + 0x7fffu + ((x.u >> 16) & 1u);   // RNE
    return (unsigned short)(r >> 16);
}
__device__ __forceinline__ float bf2f(unsigned short h) {
    union { unsigned u; float f; } x; x.u = ((unsigned)h) << 16; return x.f;
}

// ---------------------------------------------------------------------------
// Kernel 0: per-batch compaction scan of v_mask.
//  cmap[b][j]   = compacted position of key j (-1 if masked)
//  Jc[b][c]     = original index of compacted key c (S_ sentinel beyond count)
//  cumi[b][j]   = # unmasked keys <= j   (inclusive)
// ---------------------------------------------------------------------------
__global__ __launch_bounds__(256) void scan_kernel(
        const int* __restrict__ vmask, int* __restrict__ cmap,
        int* __restrict__ Jc, int* __restrict__ cumi) {
    int bb = blockIdx.x;
    const int* vm = vmask + (size_t)bb * S_;
    int t = threadIdx.x, lane = t & 63, wave = t >> 6;
    int j0 = t * 8;
    int loc[8], tot = 0;
#pragma unroll
    for (int e = 0; e < 8; e++) { loc[e] = vm[j0 + e] ? 1 : 0; tot += loc[e]; }
    int pre = tot;
#pragma unroll
    for (int d = 1; d < 64; d <<= 1) {
        int x = __shfl_up(pre, d);
        if (lane >= d) pre += x;
    }
    __shared__ int wtot[4];
    if (lane == 63) wtot[wave] = pre;
    __syncthreads();
    int wbase = 0;
    for (int w = 0; w < wave; w++) wbase += wtot[w];
    int run = wbase + pre - tot;             // exclusive prefix for this thread
    for (int e = 0; e < 8; e++) {
        int j = j0 + e;
        int before = run;
        run += loc[e];
        cumi[(size_t)bb * S_ + j] = run;
        if (loc[e]) {
            cmap[(size_t)bb * S_ + j] = before;
            Jc[(size_t)bb * S_ + before] = j;
        } else {
            cmap[(size_t)bb * S_ + j] = -1;
        }
    }
    int total = wtot[0] + wtot[1] + wtot[2] + wtot[3];
    for (int c = total + t; c < S_; c += 256) Jc[(size_t)bb * S_ + c] = S_;
}

// ---------------------------------------------------------------------------
// Kernel 1: transpose + convert weights: W[k][n] fp32 -> Wt[n][k] bf16
// ---------------------------------------------------------------------------
__global__ __launch_bounds__(256) void wtrans_kernel(
        const float* __restrict__ w0, const float* __restrict__ w1,
        const float* __restrict__ w2, unsigned short* __restrict__ wt) {
    const float* W = blockIdx.z == 0 ? w0 : (blockIdx.z == 1 ? w1 : w2);
    unsigned short* Wt = wt + (size_t)blockIdx.z * (D_ * D_);
    __shared__ float tile[32][33];
    int t = threadIdx.x;
    int k0 = blockIdx.y * 32, n0 = blockIdx.x * 32;
    int r = t >> 3, c4 = (t & 7) * 4;
    float4 v = *(const float4*)&W[(size_t)(k0 + r) * D_ + n0 + c4];
    tile[r][c4 + 0] = v.x; tile[r][c4 + 1] = v.y;
    tile[r][c4 + 2] = v.z; tile[r][c4 + 3] = v.w;
    __syncthreads();
    ushort4 o;
    o.x = f2bf(tile[c4 + 0][r]); o.y = f2bf(tile[c4 + 1][r]);
    o.z = f2bf(tile[c4 + 2][r]); o.w = f2bf(tile[c4 + 3][r]);
    *(ushort4*)&Wt[(size_t)(n0 + r) * D_ + k0 + c4] = o;
}

// ---------------------------------------------------------------------------
// Kernel 2: projection GEMM, 128x128 tile, BK=64, 4 waves (2x2), pipelined:
// regs for K-chunk kt+1 are loaded while MFMA of chunk kt runs (T14).
// fp32 A loaded directly; fp32->bf16 conversion fused at ds_write time
// (single code path; the separate conv pass + workspace-size branch removed).
// z=0 -> Qh[b][h][s][dk]
// z=1 -> Kc[b][h][c][dk]  (compacted rows via cmap; masked rows dropped)
// z=2 -> Vtc[b][h][dv][c] (compacted transposed)
// ---------------------------------------------------------------------------
__global__ __launch_bounds__(256) void proj_kernel(
        const float* __restrict__ q, const float* __restrict__ k,
        const float* __restrict__ v, const unsigned short* __restrict__ wt,
        const int* __restrict__ cmap,
        unsigned short* __restrict__ Qh, unsigned short* __restrict__ Kc,
        unsigned short* __restrict__ Vtc) {
    int z = blockIdx.z;
    const float* Af = z == 0 ? q : (z == 1 ? k : v);
    const unsigned short* Bt = wt + (size_t)z * (D_ * D_);
    int m0 = blockIdx.y * 128;
    int n0 = blockIdx.x * 128;
    __shared__ __align__(16) unsigned short As[128][72];   // 144B stride
    __shared__ __align__(16) unsigned short Bs[128][72];
    int t = threadIdx.x;
    int wave = t >> 6, lane = t & 63, lg = lane >> 4, lr = lane & 15;
    int wr = (wave >> 1) * 64, wc = (wave & 1) * 64;
    f32x4 acc[4][4];
#pragma unroll
    for (int mi = 0; mi < 4; mi++)
#pragma unroll
        for (int ni = 0; ni < 4; ni++) acc[mi][ni] = (f32x4){0.f, 0.f, 0.f, 0.f};

    int srow = t >> 3, scol = (t & 7) * 8;   // 32 rows/pass x 64 cols, 4 passes
    short8 bb2[4];
    float4 af_[4][2];
    // prologue: load K-chunk 0 into regs
#pragma unroll
    for (int i = 0; i < 4; i++) {
        int row = i * 32 + srow;
        af_[i][0] = *(const float4*)&Af[(size_t)(m0 + row) * D_ + scol];
        af_[i][1] = *(const float4*)&Af[(size_t)(m0 + row) * D_ + scol + 4];
        bb2[i] = *(const short8*)&Bt[(size_t)(n0 + row) * D_ + scol];
    }
    for (int kt = 0; kt < D_ / 64; ++kt) {
        // write staged regs -> LDS (cvt fused here)
#pragma unroll
        for (int i = 0; i < 4; i++) {
            int row = i * 32 + srow;
            short8 o;
            o[0] = (short)f2bf(af_[i][0].x); o[1] = (short)f2bf(af_[i][0].y);
            o[2] = (short)f2bf(af_[i][0].z); o[3] = (short)f2bf(af_[i][0].w);
            o[4] = (short)f2bf(af_[i][1].x); o[5] = (short)f2bf(af_[i][1].y);
            o[6] = (short)f2bf(af_[i][1].z); o[7] = (short)f2bf(af_[i][1].w);
            *(short8*)&As[row][scol] = o;
            *(short8*)&Bs[row][scol] = bb2[i];
        }
        __syncthreads();
        // issue loads for chunk kt+1 (latency hides under MFMA below)
        if (kt + 1 < D_ / 64) {
            int kk0 = (kt + 1) * 64;
#pragma unroll
            for (int i = 0; i < 4; i++) {
                int row = i * 32 + srow;
                af_[i][0] = *(const float4*)&Af[(size_t)(m0 + row) * D_ + kk0 + scol];
                af_[i][1] = *(const float4*)&Af[(size_t)(m0 + row) * D_ + kk0 + scol + 4];
                bb2[i] = *(const short8*)&Bt[(size_t)(n0 + row) * D_ + kk0 + scol];
            }
        }
        short8 af[4][2], bq[4][2];
#pragma unroll
        for (int mi = 0; mi < 4; mi++)
#pragma unroll
            for (int kh = 0; kh < 2; kh++)
                af[mi][kh] = *(const short8*)&As[wr + mi * 16 + lr][kh * 32 + lg * 8];
#pragma unroll
        for (int ni = 0; ni < 4; ni++)
#pragma unroll
            for (int kh = 0; kh < 2; kh++)
                bq[ni][kh] = *(const short8*)&Bs[wc + ni * 16 + lr][kh * 32 + lg * 8];
        __builtin_amdgcn_s_setprio(1);
#pragma unroll
        for (int kh = 0; kh < 2; kh++)
#pragma unroll
            for (int mi = 0; mi < 4; mi++)
#pragma unroll
                for (int ni = 0; ni < 4; ni++)
                    acc[mi][ni] = __builtin_amdgcn_mfma_f32_16x16x32_bf16(
                        af[mi][kh], bq[ni][kh], acc[mi][ni], 0, 0, 0);
        __builtin_amdgcn_s_setprio(0);
        __syncthreads();
    }
    // epilogue: C/D layout row=(lane>>4)*4+rr (m), col=lane&15 (n)
    if (z == 0) {
#pragma unroll
        for (int mi = 0; mi < 4; mi++) {
#pragma unroll
            for (int ni = 0; ni < 4; ni++) {
                int col = n0 + wc + ni * 16 + lr;
                int hh = col >> 6, dk = col & 63;
#pragma unroll
                for (int rr = 0; rr < 4; rr++) {
                    int m = m0 + wr + mi * 16 + lg * 4 + rr;
                    int bb = m >> 11, s = m & (S_ - 1);
                    Qh[(((size_t)(bb * H_ + hh)) * S_ + s) * 64 + dk] =
                        f2bf(acc[mi][ni][rr]);
                }
            }
        }
    } else {
        int cm_[4][4], bb_[4][4];
#pragma unroll
        for (int mi = 0; mi < 4; mi++)
#pragma unroll
            for (int rr = 0; rr < 4; rr++) {
                int m = m0 + wr + mi * 16 + lg * 4 + rr;
                int bb = m >> 11, s = m & (S_ - 1);
                bb_[mi][rr] = bb;
                cm_[mi][rr] = cmap[(size_t)bb * S_ + s];
            }
#pragma unroll
        for (int mi = 0; mi < 4; mi++) {
#pragma unroll
            for (int ni = 0; ni < 4; ni++) {
                int col = n0 + wc + ni * 16 + lr;
                int hh = col >> 6, dd = col & 63;
#pragma unroll
                for (int rr = 0; rr < 4; rr++) {
                    int c = cm_[mi][rr];
                    if (c < 0) continue;
                    int bb = bb_[mi][rr];
                    if (z == 1)
                        Kc[(((size_t)(bb * H_ + hh)) * S_ + c) * 64 + dd] =
                            f2bf(acc[mi][ni][rr]);
                    else
                        Vtc[(((size_t)(bb * H_ + hh)) * 64 + dd) * S_ + c] =
                            f2bf(acc[mi][ni][rr]);
                }
            }
        }
    }
}

// ---------------------------------------------------------------------------
// Kernel 3: causal flash attention over COMPACTED keys, QBLK=128.
// Each block owns TWO adjacent q-tiles (2p, 2p+1) sharing one K/V staging
// stream: staging+barrier cost per unit of MFMA work halves. Grid 512,
// XCD+LPT decode (heavy pairs dispatch first per XCD; K/V stays in that
// XCD's L2). K/V tile t+1 loads issue before compute of tile t (T14).
// Fully-masked extra tiles for the lower q-tile are exact (pw underflows
// to 0); degenerate prefix rows are owned by fixup_kernel as before.
// ---------------------------------------------------------------------------
__global__ __launch_bounds__(256) void attn_kernel(
        const unsigned short* __restrict__ Qh, const unsigned short* __restrict__ Kc,
        const unsigned short* __restrict__ Vtc, const int* __restrict__ Jc,
        const int* __restrict__ cumi, const int* __restrict__ qmask,
        float* __restrict__ out) {
    int fid = blockIdx.x;                   // 0..511
    int xcd = fid & 7, slot = fid >> 3;     // slot 0..63
    int pp = 15 - (slot >> 2);              // heavy q-pair first (LPT)
    int g = xcd + 8 * (slot & 3);           // 0..31 = h + 16*b
    int hh = g & 15, bb = g >> 4;
    const unsigned short* Qp = Qh + ((size_t)(bb * H_ + hh)) * S_ * 64;
    const unsigned short* Kp = Kc + ((size_t)(bb * H_ + hh)) * S_ * 64;
    const unsigned short* Vp = Vtc + ((size_t)(bb * H_ + hh)) * 64 * S_;
    const int* Jb = Jc + (size_t)bb * S_;
    int t = threadIdx.x, wave = t >> 6, lane = t & 63, lg = lane >> 4, lr = lane & 15;
    __shared__ __align__(16) unsigned short Ks[64 * 64];
    __shared__ __align__(16) unsigned short Vs[64 * 64];
    __shared__ __align__(16) unsigned short Pl[4][16][72];  // 144B stride

    int qb0 = pp * 128;
    int nc = cumi[(size_t)bb * S_ + qb0 + 127];
    int nt = (nc + 63) >> 6;
    short8 qf[2][2];
    f32x4 oacc[2][4];
    float m_run[2][4], l_run[2][4];
    int qrow[2][4];
#pragma unroll
    for (int ss = 0; ss < 2; ss++) {
        int q0 = qb0 + ss * 64 + wave * 16;
#pragma unroll
        for (int kh = 0; kh < 2; kh++)
            qf[ss][kh] = *(const short8*)&Qp[(size_t)(q0 + lr) * 64 + kh * 32 + lg * 8];
#pragma unroll
        for (int ni = 0; ni < 4; ni++) oacc[ss][ni] = (f32x4){0.f, 0.f, 0.f, 0.f};
#pragma unroll
        for (int rr = 0; rr < 4; rr++) {
            m_run[ss][rr] = -__builtin_inff(); l_run[ss][rr] = 0.f;
            qrow[ss][rr] = q0 + lg * 4 + rr;
        }
    }
    // per-thread staging geometry (2 passes x 16B)
    int soff[2], srw[2], scsw[2];
#pragma unroll
    for (int i = 0; i < 2; i++) {
        soff[i] = i * 4096 + t * 16;
        srw[i] = soff[i] >> 7;
        scsw[i] = (soff[i] & 127) ^ ((srw[i] & 7) << 4);
    }
    short8 kreg[2], vreg[2];
    if (nt > 0) {
#pragma unroll
        for (int i = 0; i < 2; i++) {
            kreg[i] = *(const short8*)((const char*)Kp + (size_t)srw[i] * 128 + scsw[i]);
            vreg[i] = *(const short8*)((const char*)Vp + (size_t)srw[i] * 4096 + scsw[i]);
        }
    }

    for (int kt = 0; kt < nt; ++kt) {
        int kv0 = kt * 64;
        // write staged regs -> LDS (swizzled layout)
#pragma unroll
        for (int i = 0; i < 2; i++) {
            *(short8*)((char*)Ks + soff[i]) = kreg[i];
            *(short8*)((char*)Vs + soff[i]) = vreg[i];
        }
        __syncthreads();
        // issue next tile's loads; latency hides under 2x QK/softmax/PV
        if (kt + 1 < nt) {
            int kv0n = (kt + 1) * 64;
#pragma unroll
            for (int i = 0; i < 2; i++) {
                kreg[i] = *(const short8*)((const char*)Kp + (size_t)(kv0n + srw[i]) * 128 + scsw[i]);
                vreg[i] = *(const short8*)((const char*)Vp + (size_t)srw[i] * 4096 + kv0n * 2 + scsw[i]);
            }
        }
        // original key indices for this tile (shared by both q-sets)
        int jo[4];
#pragma unroll
        for (int ni = 0; ni < 4; ni++) jo[ni] = Jb[kv0 + ni * 16 + lr];

#pragma unroll
        for (int ss = 0; ss < 2; ss++) {
            f32x4 sacc[4];
#pragma unroll
            for (int ni = 0; ni < 4; ni++) sacc[ni] = (f32x4){0.f, 0.f, 0.f, 0.f};
            __builtin_amdgcn_s_setprio(1);
#pragma unroll
            for (int ni = 0; ni < 4; ni++) {
                int row = ni * 16 + lr;
#pragma unroll
                for (int kh = 0; kh < 2; kh++) {
                    int cb = (kh * 64 + lg * 16) ^ ((row & 7) << 4);
                    short8 kf = *(const short8*)((const char*)Ks + row * 128 + cb);
                    sacc[ni] = __builtin_amdgcn_mfma_f32_16x16x32_bf16(qf[ss][kh], kf, sacc[ni], 0, 0, 0);
                }
            }
            __builtin_amdgcn_s_setprio(0);
            // scale + causal mask on ORIGINAL index (sentinel S_ for pad)
            float sv[4][4];
#pragma unroll
            for (int ni = 0; ni < 4; ni++)
#pragma unroll
                for (int rr = 0; rr < 4; rr++) {
                    float s = sacc[ni][rr] * 0.125f;
                    if (jo[ni] > qrow[ss][rr]) s -= MAXV;
                    sv[ni][rr] = s;
                }
            float scl[4];
#pragma unroll
            for (int rr = 0; rr < 4; rr++) {
                float a = fmaxf(fmaxf(sv[0][rr], sv[1][rr]), fmaxf(sv[2][rr], sv[3][rr]));
#pragma unroll
                for (int d = 1; d < 16; d <<= 1) a = fmaxf(a, __shfl_xor(a, d));
                float mn = fmaxf(m_run[ss][rr], a);
                scl[rr] = __expf(m_run[ss][rr] - mn);
                m_run[ss][rr] = mn;
            }
            float pw[4][4], ps[4];
#pragma unroll
            for (int rr = 0; rr < 4; rr++) ps[rr] = 0.f;
#pragma unroll
            for (int ni = 0; ni < 4; ni++)
#pragma unroll
                for (int rr = 0; rr < 4; rr++) {
                    pw[ni][rr] = __expf(sv[ni][rr] - m_run[ss][rr]);
                    ps[rr] += pw[ni][rr];
                }
#pragma unroll
            for (int rr = 0; rr < 4; rr++) {
#pragma unroll
                for (int d = 1; d < 16; d <<= 1) ps[rr] += __shfl_xor(ps[rr], d);
                l_run[ss][rr] = l_run[ss][rr] * scl[rr] + ps[rr];
            }
#pragma unroll
            for (int ni = 0; ni < 4; ni++)
#pragma unroll
                for (int rr = 0; rr < 4; rr++) oacc[ss][ni][rr] *= scl[rr];
#pragma unroll
            for (int ni = 0; ni < 4; ni++)
#pragma unroll
                for (int rr = 0; rr < 4; rr++)
                    Pl[wave][lg * 4 + rr][ni * 16 + lr] = f2bf(pw[ni][rr]);
            short8 pa[2];
#pragma unroll
            for (int kh = 0; kh < 2; kh++)
                pa[kh] = *(const short8*)&Pl[wave][lr][kh * 32 + lg * 8];
            __builtin_amdgcn_s_setprio(1);
#pragma unroll
            for (int ni = 0; ni < 4; ni++) {
                int rowd = ni * 16 + lr;
#pragma unroll
                for (int kh = 0; kh < 2; kh++) {
                    int cb = (kh * 64 + lg * 16) ^ ((rowd & 7) << 4);
                    short8 vf = *(const short8*)((const char*)Vs + rowd * 128 + cb);
                    oacc[ss][ni] = __builtin_amdgcn_mfma_f32_16x16x32_bf16(pa[kh], vf, oacc[ss][ni], 0, 0, 0);
                }
            }
            __builtin_amdgcn_s_setprio(0);
        }
        __syncthreads();
    }
    // epilogue
#pragma unroll
    for (int ss = 0; ss < 2; ss++)
#pragma unroll
        for (int rr = 0; rr < 4; rr++) {
            int qm = qmask[bb * S_ + qrow[ss][rr]];
            float f = (qm != 0 && l_run[ss][rr] > 0.f) ? (float)qm / l_run[ss][rr] : 0.f;
#pragma unroll
            for (int ni = 0; ni < 4; ni++)
                out[((size_t)(bb * S_ + qrow[ss][rr])) * D_ + hh * 64 + ni * 16 + lr] =
                    oacc[ss][ni][rr] * f;
        }
}

// ---------------------------------------------------------------------------
// Kernel 4: degenerate-row fixup (rows r < d = first unmasked key).
// out[r][p] = (sum_{j<=r} vh[j][p] + sum_all_compacted vh[.][p]) / (r+1+ccount)
// prefix vh recomputed from v . Wt (masked rows are not in compacted V).
// ---------------------------------------------------------------------------
__global__ __launch_bounds__(256) void fixup_kernel(
        const int* __restrict__ qmask, const float* __restrict__ v,
        const unsigned short* __restrict__ wt, const unsigned short* __restrict__ Vtc,
        const int* __restrict__ Jc, const int* __restrict__ cumi,
        float* __restrict__ out) {
    int bb = blockIdx.y;
    int p0 = blockIdx.x * 16;
    int t = threadIdx.x;
    int pl = t >> 4, jl = t & 15;
    int d = Jc[(size_t)bb * S_];                 // first unmasked key (S_ if none)
    if (d == 0) return;
    int ccount = cumi[(size_t)bb * S_ + S_ - 1];
    int p = p0 + pl;
    int hh = p >> 6, dv = p & 63;
    const unsigned short* vrow = Vtc + ((size_t)(bb * H_ + hh) * 64 + dv) * S_;
    float suf = 0.f;
    for (int c = jl; c < ccount; c += 16) suf += bf2f(vrow[c]);
#pragma unroll
    for (int dd = 1; dd < 16; dd <<= 1) suf += __shfl_xor(suf, dd);
    // prefix rows on the fly: vh[r][p] = v[b][r][:] . Wv[:][p] (bf16 weights)
    const unsigned short* wcol = wt + 2ull * D_ * D_ + (size_t)p * D_;  // Wv^T row p
    float pre = 0.f;
    for (int r = 0; r < d; ++r) {
        const float* vr = v + ((size_t)bb * S_ + r) * D_;
        float acc = 0.f;
        for (int kk = jl * 64; kk < jl * 64 + 64; kk += 8) {
            float4 a1 = *(const float4*)&vr[kk];
            float4 a2 = *(const float4*)&vr[kk + 4];
            acc += a1.x * bf2f(wcol[kk + 0]) + a1.y * bf2f(wcol[kk + 1]) +
                   a1.z * bf2f(wcol[kk + 2]) + a1.w * bf2f(wcol[kk + 3]) +
                   a2.x * bf2f(wcol[kk + 4]) + a2.y * bf2f(wcol[kk + 5]) +
                   a2.z * bf2f(wcol[kk + 6]) + a2.w * bf2f(wcol[kk + 7]);
        }
#pragma unroll
        for (int dd = 1; dd < 16; dd <<= 1) acc += __shfl_xor(acc, dd);
        pre += acc;
        if (jl == 0 && qmask[(size_t)bb * S_ + r] != 0)
            out[((size_t)(bb * S_ + r)) * D_ + p] =
                (pre + suf) / (float)(r + 1 + ccount);
    }
}

// ---------------------------------------------------------------------------
extern "C" void kernel_launch(void* const* d_in, const int* in_sizes, int n_in,
                              void* d_out, int out_size, void* d_ws, size_t ws_size,
                              hipStream_t stream) {
    const float* q  = (const float*)d_in[0];
    const float* k  = (const float*)d_in[1];
    const float* v  = (const float*)d_in[2];
    const int* vmask = (const int*)d_in[3];
    const int* qmask = (const int*)d_in[4];
    const float* Wq = (const float*)d_in[5];
    const float* Wk = (const float*)d_in[6];
    const float* Wv = (const float*)d_in[7];
    float* out = (float*)d_out;

    char* ws = (char*)d_ws;
    const size_t MB = 1024ull * 1024;
    int* cmap = (int*)ws;                                   // 16 KB
    int* Jc   = (int*)(ws + 16 * 1024);                     // 16 KB
    int* cumi = (int*)(ws + 32 * 1024);                     // 16 KB
    unsigned short* Wt  = (unsigned short*)(ws + 64 * 1024);          // 6 MB
    unsigned short* Qh  = (unsigned short*)(ws + 64 * 1024 + 6 * MB); // 8 MB
    unsigned short* Kc  = (unsigned short*)(ws + 64 * 1024 + 14 * MB);// 8 MB
    unsigned short* Vtc = (unsigned short*)(ws + 64 * 1024 + 22 * MB);// 8 MB

    scan_kernel<<<dim3(2), 256, 0, stream>>>(vmask, cmap, Jc, cumi);
    wtrans_kernel<<<dim3(32, 32, 3), 256, 0, stream>>>(Wq, Wk, Wv, Wt);
    proj_kernel<<<dim3(8, 32, 3), 256, 0, stream>>>(q, k, v, Wt, cmap, Qh, Kc, Vtc);
    attn_kernel<<<dim3(512), 256, 0, stream>>>(Qh, Kc, Vtc, Jc, cumi, qmask, out);
    fixup_kernel<<<dim3(64, 2), 256, 0, stream>>>(qmask, v, Wt, Vtc, Jc, cumi, out);
}

// Round 11
// 230.796 us; speedup vs baseline: 1.0412x; 1.0412x over previous
//
#include <hip/hip_runtime.h>
#include <hip/hip_bf16.h>

// Problem constants (B=2, S=2048, D=1024, H=16, DK=DV=64)
#define H_    16
#define S_    2048
#define D_    1024
#define MAXV  1e10f

typedef __attribute__((ext_vector_type(8))) short short8;
typedef __attribute__((ext_vector_type(4))) float f32x4;

__device__ __forceinline__ unsigned short f2bf(float f) {
    union { float f; unsigned u; } x; x.f = f;
    unsigned r = x.u + 0x7fffu + ((x.u >> 16) & 1u);   // RNE
    return (unsigned short)(r >> 16);
}
__device__ __forceinline__ float bf2f(unsigned short h) {
    union { unsigned u; float f; } x; x.u = ((unsigned)h) << 16; return x.f;
}

// ---------------------------------------------------------------------------
// Kernel 0: per-batch compaction scan of v_mask.
//  cmap[b][j]   = compacted position of key j (-1 if masked)
//  Jc[b][c]     = original index of compacted key c (S_ sentinel beyond count)
//  cumi[b][j]   = # unmasked keys <= j   (inclusive)
// ---------------------------------------------------------------------------
__global__ __launch_bounds__(256) void scan_kernel(
        const int* __restrict__ vmask, int* __restrict__ cmap,
        int* __restrict__ Jc, int* __restrict__ cumi) {
    int bb = blockIdx.x;
    const int* vm = vmask + (size_t)bb * S_;
    int t = threadIdx.x, lane = t & 63, wave = t >> 6;
    int j0 = t * 8;
    int loc[8], tot = 0;
#pragma unroll
    for (int e = 0; e < 8; e++) { loc[e] = vm[j0 + e] ? 1 : 0; tot += loc[e]; }
    int pre = tot;
#pragma unroll
    for (int d = 1; d < 64; d <<= 1) {
        int x = __shfl_up(pre, d);
        if (lane >= d) pre += x;
    }
    __shared__ int wtot[4];
    if (lane == 63) wtot[wave] = pre;
    __syncthreads();
    int wbase = 0;
    for (int w = 0; w < wave; w++) wbase += wtot[w];
    int run = wbase + pre - tot;             // exclusive prefix for this thread
    for (int e = 0; e < 8; e++) {
        int j = j0 + e;
        int before = run;
        run += loc[e];
        cumi[(size_t)bb * S_ + j] = run;
        if (loc[e]) {
            cmap[(size_t)bb * S_ + j] = before;
            Jc[(size_t)bb * S_ + before] = j;
        } else {
            cmap[(size_t)bb * S_ + j] = -1;
        }
    }
    int total = wtot[0] + wtot[1] + wtot[2] + wtot[3];
    for (int c = total + t; c < S_; c += 256) Jc[(size_t)bb * S_ + c] = S_;
}

// ---------------------------------------------------------------------------
// Kernel 1: transpose + convert weights: W[k][n] fp32 -> Wt[n][k] bf16
// ---------------------------------------------------------------------------
__global__ __launch_bounds__(256) void wtrans_kernel(
        const float* __restrict__ w0, const float* __restrict__ w1,
        const float* __restrict__ w2, unsigned short* __restrict__ wt) {
    const float* W = blockIdx.z == 0 ? w0 : (blockIdx.z == 1 ? w1 : w2);
    unsigned short* Wt = wt + (size_t)blockIdx.z * (D_ * D_);
    __shared__ float tile[32][33];
    int t = threadIdx.x;
    int k0 = blockIdx.y * 32, n0 = blockIdx.x * 32;
    int r = t >> 3, c4 = (t & 7) * 4;
    float4 v = *(const float4*)&W[(size_t)(k0 + r) * D_ + n0 + c4];
    tile[r][c4 + 0] = v.x; tile[r][c4 + 1] = v.y;
    tile[r][c4 + 2] = v.z; tile[r][c4 + 3] = v.w;
    __syncthreads();
    ushort4 o;
    o.x = f2bf(tile[c4 + 0][r]); o.y = f2bf(tile[c4 + 1][r]);
    o.z = f2bf(tile[c4 + 2][r]); o.w = f2bf(tile[c4 + 3][r]);
    *(ushort4*)&Wt[(size_t)(n0 + r) * D_ + k0 + c4] = o;
}

// ---------------------------------------------------------------------------
// Kernel 1b: convert q/k/v fp32 -> bf16 flat (restored: measured round 9 vs
// 10, the bf16 staging copy saves ~22us inside proj for ~13us of BW work).
// ---------------------------------------------------------------------------
__global__ __launch_bounds__(256) void conv_kernel(
        const float* __restrict__ q, const float* __restrict__ k,
        const float* __restrict__ v, unsigned short* __restrict__ abf) {
    int z = blockIdx.y;
    const float* src = z == 0 ? q : (z == 1 ? k : v);
    unsigned short* dst = abf + (size_t)z * (4096ull * 1024);
    size_t i = ((size_t)blockIdx.x * 256 + threadIdx.x) * 8;
    float4 f1 = *(const float4*)&src[i];
    float4 f2 = *(const float4*)&src[i + 4];
    short8 o;
    o[0] = (short)f2bf(f1.x); o[1] = (short)f2bf(f1.y);
    o[2] = (short)f2bf(f1.z); o[3] = (short)f2bf(f1.w);
    o[4] = (short)f2bf(f2.x); o[5] = (short)f2bf(f2.y);
    o[6] = (short)f2bf(f2.z); o[7] = (short)f2bf(f2.w);
    *(short8*)&dst[i] = o;
}

// ---------------------------------------------------------------------------
// Kernel 2: projection GEMM, 128x128 tile, BK=64, 4 waves (2x2), pipelined:
// regs for K-chunk kt+1 are loaded while MFMA of chunk kt runs (T14).
// PRE=true: A pre-converted bf16 (no VALU cvt in loop). PRE=false: fp32+cvt.
// z=0 -> Qh[b][h][s][dk]
// z=1 -> Kc[b][h][c][dk]  (compacted rows via cmap; masked rows dropped)
// z=2 -> Vtc[b][h][dv][c] (compacted transposed)
// ---------------------------------------------------------------------------
template <bool PRE>
__global__ __launch_bounds__(256) void proj_kernel(
        const float* __restrict__ q, const float* __restrict__ k,
        const float* __restrict__ v, const unsigned short* __restrict__ abf,
        const unsigned short* __restrict__ wt, const int* __restrict__ cmap,
        unsigned short* __restrict__ Qh, unsigned short* __restrict__ Kc,
        unsigned short* __restrict__ Vtc) {
    int z = blockIdx.z;
    const float* Af = z == 0 ? q : (z == 1 ? k : v);
    const unsigned short* Ab = abf + (size_t)z * (4096ull * 1024);
    const unsigned short* Bt = wt + (size_t)z * (D_ * D_);
    int m0 = blockIdx.y * 128;
    int n0 = blockIdx.x * 128;
    __shared__ __align__(16) unsigned short As[128][72];   // 144B stride
    __shared__ __align__(16) unsigned short Bs[128][72];
    int t = threadIdx.x;
    int wave = t >> 6, lane = t & 63, lg = lane >> 4, lr = lane & 15;
    int wr = (wave >> 1) * 64, wc = (wave & 1) * 64;
    f32x4 acc[4][4];
#pragma unroll
    for (int mi = 0; mi < 4; mi++)
#pragma unroll
        for (int ni = 0; ni < 4; ni++) acc[mi][ni] = (f32x4){0.f, 0.f, 0.f, 0.f};

    int srow = t >> 3, scol = (t & 7) * 8;   // 32 rows/pass x 64 cols, 4 passes
    short8 aa[4], bb2[4];
    float4 af_[4][2];
    // prologue: load K-chunk 0 into regs
#pragma unroll
    for (int i = 0; i < 4; i++) {
        int row = i * 32 + srow;
        if (PRE) {
            aa[i] = *(const short8*)&Ab[(size_t)(m0 + row) * D_ + scol];
        } else {
            af_[i][0] = *(const float4*)&Af[(size_t)(m0 + row) * D_ + scol];
            af_[i][1] = *(const float4*)&Af[(size_t)(m0 + row) * D_ + scol + 4];
        }
        bb2[i] = *(const short8*)&Bt[(size_t)(n0 + row) * D_ + scol];
    }
    for (int kt = 0; kt < D_ / 64; ++kt) {
        // write staged regs -> LDS
#pragma unroll
        for (int i = 0; i < 4; i++) {
            int row = i * 32 + srow;
            if (PRE) {
                *(short8*)&As[row][scol] = aa[i];
            } else {
                short8 o;
                o[0] = (short)f2bf(af_[i][0].x); o[1] = (short)f2bf(af_[i][0].y);
                o[2] = (short)f2bf(af_[i][0].z); o[3] = (short)f2bf(af_[i][0].w);
                o[4] = (short)f2bf(af_[i][1].x); o[5] = (short)f2bf(af_[i][1].y);
                o[6] = (short)f2bf(af_[i][1].z); o[7] = (short)f2bf(af_[i][1].w);
                *(short8*)&As[row][scol] = o;
            }
            *(short8*)&Bs[row][scol] = bb2[i];
        }
        __syncthreads();
        // issue loads for chunk kt+1 (latency hides under MFMA below)
        if (kt + 1 < D_ / 64) {
            int kk0 = (kt + 1) * 64;
#pragma unroll
            for (int i = 0; i < 4; i++) {
                int row = i * 32 + srow;
                if (PRE) {
                    aa[i] = *(const short8*)&Ab[(size_t)(m0 + row) * D_ + kk0 + scol];
                } else {
                    af_[i][0] = *(const float4*)&Af[(size_t)(m0 + row) * D_ + kk0 + scol];
                    af_[i][1] = *(const float4*)&Af[(size_t)(m0 + row) * D_ + kk0 + scol + 4];
                }
                bb2[i] = *(const short8*)&Bt[(size_t)(n0 + row) * D_ + kk0 + scol];
            }
        }
        short8 af[4][2], bq[4][2];
#pragma unroll
        for (int mi = 0; mi < 4; mi++)
#pragma unroll
            for (int kh = 0; kh < 2; kh++)
                af[mi][kh] = *(const short8*)&As[wr + mi * 16 + lr][kh * 32 + lg * 8];
#pragma unroll
        for (int ni = 0; ni < 4; ni++)
#pragma unroll
            for (int kh = 0; kh < 2; kh++)
                bq[ni][kh] = *(const short8*)&Bs[wc + ni * 16 + lr][kh * 32 + lg * 8];
        __builtin_amdgcn_s_setprio(1);
#pragma unroll
        for (int kh = 0; kh < 2; kh++)
#pragma unroll
            for (int mi = 0; mi < 4; mi++)
#pragma unroll
                for (int ni = 0; ni < 4; ni++)
                    acc[mi][ni] = __builtin_amdgcn_mfma_f32_16x16x32_bf16(
                        af[mi][kh], bq[ni][kh], acc[mi][ni], 0, 0, 0);
        __builtin_amdgcn_s_setprio(0);
        __syncthreads();
    }
    // epilogue: C/D layout row=(lane>>4)*4+rr (m), col=lane&15 (n)
    if (z == 0) {
#pragma unroll
        for (int mi = 0; mi < 4; mi++) {
#pragma unroll
            for (int ni = 0; ni < 4; ni++) {
                int col = n0 + wc + ni * 16 + lr;
                int hh = col >> 6, dk = col & 63;
#pragma unroll
                for (int rr = 0; rr < 4; rr++) {
                    int m = m0 + wr + mi * 16 + lg * 4 + rr;
                    int bb = m >> 11, s = m & (S_ - 1);
                    Qh[(((size_t)(bb * H_ + hh)) * S_ + s) * 64 + dk] =
                        f2bf(acc[mi][ni][rr]);
                }
            }
        }
    } else {
        int cm_[4][4], bb_[4][4];
#pragma unroll
        for (int mi = 0; mi < 4; mi++)
#pragma unroll
            for (int rr = 0; rr < 4; rr++) {
                int m = m0 + wr + mi * 16 + lg * 4 + rr;
                int bb = m >> 11, s = m & (S_ - 1);
                bb_[mi][rr] = bb;
                cm_[mi][rr] = cmap[(size_t)bb * S_ + s];
            }
#pragma unroll
        for (int mi = 0; mi < 4; mi++) {
#pragma unroll
            for (int ni = 0; ni < 4; ni++) {
                int col = n0 + wc + ni * 16 + lr;
                int hh = col >> 6, dd = col & 63;
#pragma unroll
                for (int rr = 0; rr < 4; rr++) {
                    int c = cm_[mi][rr];
                    if (c < 0) continue;
                    int bb = bb_[mi][rr];
                    if (z == 1)
                        Kc[(((size_t)(bb * H_ + hh)) * S_ + c) * 64 + dd] =
                            f2bf(acc[mi][ni][rr]);
                    else
                        Vtc[(((size_t)(bb * H_ + hh)) * 64 + dd) * S_ + c] =
                            f2bf(acc[mi][ni][rr]);
                }
            }
        }
    }
}

// ---------------------------------------------------------------------------
// Kernel 3: causal flash attention over COMPACTED keys, QBLK=128.
// Each block owns TWO adjacent q-tiles (2p, 2p+1) sharing one K/V staging
// stream: staging+barrier cost per unit of MFMA work halves. Grid 512,
// XCD+LPT decode (heavy pairs dispatch first per XCD; K/V stays in that
// XCD's L2). K/V tile t+1 loads issue before compute of tile t (T14).
// ---------------------------------------------------------------------------
__global__ __launch_bounds__(256) void attn_kernel(
        const unsigned short* __restrict__ Qh, const unsigned short* __restrict__ Kc,
        const unsigned short* __restrict__ Vtc, const int* __restrict__ Jc,
        const int* __restrict__ cumi, const int* __restrict__ qmask,
        float* __restrict__ out) {
    int fid = blockIdx.x;                   // 0..511
    int xcd = fid & 7, slot = fid >> 3;     // slot 0..63
    int pp = 15 - (slot >> 2);              // heavy q-pair first (LPT)
    int g = xcd + 8 * (slot & 3);           // 0..31 = h + 16*b
    int hh = g & 15, bb = g >> 4;
    const unsigned short* Qp = Qh + ((size_t)(bb * H_ + hh)) * S_ * 64;
    const unsigned short* Kp = Kc + ((size_t)(bb * H_ + hh)) * S_ * 64;
    const unsigned short* Vp = Vtc + ((size_t)(bb * H_ + hh)) * 64 * S_;
    const int* Jb = Jc + (size_t)bb * S_;
    int t = threadIdx.x, wave = t >> 6, lane = t & 63, lg = lane >> 4, lr = lane & 15;
    __shared__ __align__(16) unsigned short Ks[64 * 64];
    __shared__ __align__(16) unsigned short Vs[64 * 64];
    __shared__ __align__(16) unsigned short Pl[4][16][72];  // 144B stride

    int qb0 = pp * 128;
    int nc = cumi[(size_t)bb * S_ + qb0 + 127];
    int nt = (nc + 63) >> 6;
    short8 qf[2][2];
    f32x4 oacc[2][4];
    float m_run[2][4], l_run[2][4];
    int qrow[2][4];
#pragma unroll
    for (int ss = 0; ss < 2; ss++) {
        int q0 = qb0 + ss * 64 + wave * 16;
#pragma unroll
        for (int kh = 0; kh < 2; kh++)
            qf[ss][kh] = *(const short8*)&Qp[(size_t)(q0 + lr) * 64 + kh * 32 + lg * 8];
#pragma unroll
        for (int ni = 0; ni < 4; ni++) oacc[ss][ni] = (f32x4){0.f, 0.f, 0.f, 0.f};
#pragma unroll
        for (int rr = 0; rr < 4; rr++) {
            m_run[ss][rr] = -__builtin_inff(); l_run[ss][rr] = 0.f;
            qrow[ss][rr] = q0 + lg * 4 + rr;
        }
    }
    // per-thread staging geometry (2 passes x 16B)
    int soff[2], srw[2], scsw[2];
#pragma unroll
    for (int i = 0; i < 2; i++) {
        soff[i] = i * 4096 + t * 16;
        srw[i] = soff[i] >> 7;
        scsw[i] = (soff[i] & 127) ^ ((srw[i] & 7) << 4);
    }
    short8 kreg[2], vreg[2];
    if (nt > 0) {
#pragma unroll
        for (int i = 0; i < 2; i++) {
            kreg[i] = *(const short8*)((const char*)Kp + (size_t)srw[i] * 128 + scsw[i]);
            vreg[i] = *(const short8*)((const char*)Vp + (size_t)srw[i] * 4096 + scsw[i]);
        }
    }

    for (int kt = 0; kt < nt; ++kt) {
        int kv0 = kt * 64;
        // write staged regs -> LDS (swizzled layout)
#pragma unroll
        for (int i = 0; i < 2; i++) {
            *(short8*)((char*)Ks + soff[i]) = kreg[i];
            *(short8*)((char*)Vs + soff[i]) = vreg[i];
        }
        __syncthreads();
        // issue next tile's loads; latency hides under 2x QK/softmax/PV
        if (kt + 1 < nt) {
            int kv0n = (kt + 1) * 64;
#pragma unroll
            for (int i = 0; i < 2; i++) {
                kreg[i] = *(const short8*)((const char*)Kp + (size_t)(kv0n + srw[i]) * 128 + scsw[i]);
                vreg[i] = *(const short8*)((const char*)Vp + (size_t)srw[i] * 4096 + kv0n * 2 + scsw[i]);
            }
        }
        // original key indices for this tile (shared by both q-sets)
        int jo[4];
#pragma unroll
        for (int ni = 0; ni < 4; ni++) jo[ni] = Jb[kv0 + ni * 16 + lr];

#pragma unroll
        for (int ss = 0; ss < 2; ss++) {
            f32x4 sacc[4];
#pragma unroll
            for (int ni = 0; ni < 4; ni++) sacc[ni] = (f32x4){0.f, 0.f, 0.f, 0.f};
            __builtin_amdgcn_s_setprio(1);
#pragma unroll
            for (int ni = 0; ni < 4; ni++) {
                int row = ni * 16 + lr;
#pragma unroll
                for (int kh = 0; kh < 2; kh++) {
                    int cb = (kh * 64 + lg * 16) ^ ((row & 7) << 4);
                    short8 kf = *(const short8*)((const char*)Ks + row * 128 + cb);
                    sacc[ni] = __builtin_amdgcn_mfma_f32_16x16x32_bf16(qf[ss][kh], kf, sacc[ni], 0, 0, 0);
                }
            }
            __builtin_amdgcn_s_setprio(0);
            // scale + causal mask on ORIGINAL index (sentinel S_ for pad)
            float sv[4][4];
#pragma unroll
            for (int ni = 0; ni < 4; ni++)
#pragma unroll
                for (int rr = 0; rr < 4; rr++) {
                    float s = sacc[ni][rr] * 0.125f;
                    if (jo[ni] > qrow[ss][rr]) s -= MAXV;
                    sv[ni][rr] = s;
                }
            float scl[4];
#pragma unroll
            for (int rr = 0; rr < 4; rr++) {
                float a = fmaxf(fmaxf(sv[0][rr], sv[1][rr]), fmaxf(sv[2][rr], sv[3][rr]));
#pragma unroll
                for (int d = 1; d < 16; d <<= 1) a = fmaxf(a, __shfl_xor(a, d));
                float mn = fmaxf(m_run[ss][rr], a);
                scl[rr] = __expf(m_run[ss][rr] - mn);
                m_run[ss][rr] = mn;
            }
            float pw[4][4], ps[4];
#pragma unroll
            for (int rr = 0; rr < 4; rr++) ps[rr] = 0.f;
#pragma unroll
            for (int ni = 0; ni < 4; ni++)
#pragma unroll
                for (int rr = 0; rr < 4; rr++) {
                    pw[ni][rr] = __expf(sv[ni][rr] - m_run[ss][rr]);
                    ps[rr] += pw[ni][rr];
                }
#pragma unroll
            for (int rr = 0; rr < 4; rr++) {
#pragma unroll
                for (int d = 1; d < 16; d <<= 1) ps[rr] += __shfl_xor(ps[rr], d);
                l_run[ss][rr] = l_run[ss][rr] * scl[rr] + ps[rr];
            }
#pragma unroll
            for (int ni = 0; ni < 4; ni++)
#pragma unroll
                for (int rr = 0; rr < 4; rr++) oacc[ss][ni][rr] *= scl[rr];
#pragma unroll
            for (int ni = 0; ni < 4; ni++)
#pragma unroll
                for (int rr = 0; rr < 4; rr++)
                    Pl[wave][lg * 4 + rr][ni * 16 + lr] = f2bf(pw[ni][rr]);
            short8 pa[2];
#pragma unroll
            for (int kh = 0; kh < 2; kh++)
                pa[kh] = *(const short8*)&Pl[wave][lr][kh * 32 + lg * 8];
            __builtin_amdgcn_s_setprio(1);
#pragma unroll
            for (int ni = 0; ni < 4; ni++) {
                int rowd = ni * 16 + lr;
#pragma unroll
                for (int kh = 0; kh < 2; kh++) {
                    int cb = (kh * 64 + lg * 16) ^ ((rowd & 7) << 4);
                    short8 vf = *(const short8*)((const char*)Vs + rowd * 128 + cb);
                    oacc[ss][ni] = __builtin_amdgcn_mfma_f32_16x16x32_bf16(pa[kh], vf, oacc[ss][ni], 0, 0, 0);
                }
            }
            __builtin_amdgcn_s_setprio(0);
        }
        __syncthreads();
    }
    // epilogue
#pragma unroll
    for (int ss = 0; ss < 2; ss++)
#pragma unroll
        for (int rr = 0; rr < 4; rr++) {
            int qm = qmask[bb * S_ + qrow[ss][rr]];
            float f = (qm != 0 && l_run[ss][rr] > 0.f) ? (float)qm / l_run[ss][rr] : 0.f;
#pragma unroll
            for (int ni = 0; ni < 4; ni++)
                out[((size_t)(bb * S_ + qrow[ss][rr])) * D_ + hh * 64 + ni * 16 + lr] =
                    oacc[ss][ni][rr] * f;
        }
}

// ---------------------------------------------------------------------------
// Kernel 4: degenerate-row fixup (rows r < d = first unmasked key).
// out[r][p] = (sum_{j<=r} vh[j][p] + sum_all_compacted vh[.][p]) / (r+1+ccount)
// prefix vh recomputed from v . Wt (masked rows are not in compacted V).
// ---------------------------------------------------------------------------
__global__ __launch_bounds__(256) void fixup_kernel(
        const int* __restrict__ qmask, const float* __restrict__ v,
        const unsigned short* __restrict__ wt, const unsigned short* __restrict__ Vtc,
        const int* __restrict__ Jc, const int* __restrict__ cumi,
        float* __restrict__ out) {
    int bb = blockIdx.y;
    int p0 = blockIdx.x * 16;
    int t = threadIdx.x;
    int pl = t >> 4, jl = t & 15;
    int d = Jc[(size_t)bb * S_];                 // first unmasked key (S_ if none)
    if (d == 0) return;
    int ccount = cumi[(size_t)bb * S_ + S_ - 1];
    int p = p0 + pl;
    int hh = p >> 6, dv = p & 63;
    const unsigned short* vrow = Vtc + ((size_t)(bb * H_ + hh) * 64 + dv) * S_;
    float suf = 0.f;
    for (int c = jl; c < ccount; c += 16) suf += bf2f(vrow[c]);
#pragma unroll
    for (int dd = 1; dd < 16; dd <<= 1) suf += __shfl_xor(suf, dd);
    // prefix rows on the fly: vh[r][p] = v[b][r][:] . Wv[:][p] (bf16 weights)
    const unsigned short* wcol = wt + 2ull * D_ * D_ + (size_t)p * D_;  // Wv^T row p
    float pre = 0.f;
    for (int r = 0; r < d; ++r) {
        const float* vr = v + ((size_t)bb * S_ + r) * D_;
        float acc = 0.f;
        for (int kk = jl * 64; kk < jl * 64 + 64; kk += 8) {
            float4 a1 = *(const float4*)&vr[kk];
            float4 a2 = *(const float4*)&vr[kk + 4];
            acc += a1.x * bf2f(wcol[kk + 0]) + a1.y * bf2f(wcol[kk + 1]) +
                   a1.z * bf2f(wcol[kk + 2]) + a1.w * bf2f(wcol[kk + 3]) +
                   a2.x * bf2f(wcol[kk + 4]) + a2.y * bf2f(wcol[kk + 5]) +
                   a2.z * bf2f(wcol[kk + 6]) + a2.w * bf2f(wcol[kk + 7]);
        }
#pragma unroll
        for (int dd = 1; dd < 16; dd <<= 1) acc += __shfl_xor(acc, dd);
        pre += acc;
        if (jl == 0 && qmask[(size_t)bb * S_ + r] != 0)
            out[((size_t)(bb * S_ + r)) * D_ + p] =
                (pre + suf) / (float)(r + 1 + ccount);
    }
}

// ---------------------------------------------------------------------------
extern "C" void kernel_launch(void* const* d_in, const int* in_sizes, int n_in,
                              void* d_out, int out_size, void* d_ws, size_t ws_size,
                              hipStream_t stream) {
    const float* q  = (const float*)d_in[0];
    const float* k  = (const float*)d_in[1];
    const float* v  = (const float*)d_in[2];
    const int* vmask = (const int*)d_in[3];
    const int* qmask = (const int*)d_in[4];
    const float* Wq = (const float*)d_in[5];
    const float* Wk = (const float*)d_in[6];
    const float* Wv = (const float*)d_in[7];
    float* out = (float*)d_out;

    char* ws = (char*)d_ws;
    const size_t MB = 1024ull * 1024;
    int* cmap = (int*)ws;                                   // 16 KB
    int* Jc   = (int*)(ws + 16 * 1024);                     // 16 KB
    int* cumi = (int*)(ws + 32 * 1024);                     // 16 KB
    unsigned short* Wt  = (unsigned short*)(ws + 64 * 1024);          // 6 MB
    unsigned short* Qh  = (unsigned short*)(ws + 64 * 1024 + 6 * MB); // 8 MB
    unsigned short* Kc  = (unsigned short*)(ws + 64 * 1024 + 14 * MB);// 8 MB
    unsigned short* Vtc = (unsigned short*)(ws + 64 * 1024 + 22 * MB);// 8 MB
    unsigned short* Abf = (unsigned short*)(ws + 64 * 1024 + 30 * MB);// 24 MB
    bool pre = ws_size >= 64 * 1024 + 54 * MB;

    scan_kernel<<<dim3(2), 256, 0, stream>>>(vmask, cmap, Jc, cumi);
    wtrans_kernel<<<dim3(32, 32, 3), 256, 0, stream>>>(Wq, Wk, Wv, Wt);
    if (pre) {
        conv_kernel<<<dim3(2048, 3), 256, 0, stream>>>(q, k, v, Abf);
        proj_kernel<true><<<dim3(8, 32, 3), 256, 0, stream>>>(
            q, k, v, Abf, Wt, cmap, Qh, Kc, Vtc);
    } else {
        proj_kernel<false><<<dim3(8, 32, 3), 256, 0, stream>>>(
            q, k, v, Abf, Wt, cmap, Qh, Kc, Vtc);
    }
    attn_kernel<<<dim3(512), 256, 0, stream>>>(Qh, Kc, Vtc, Jc, cumi, qmask, out);
    fixup_kernel<<<dim3(64, 2), 256, 0, stream>>>(qmask, v, Wt, Vtc, Jc, cumi, out);
}

// Round 12
// 211.522 us; speedup vs baseline: 1.1361x; 1.0911x over previous
//
#include <hip/hip_runtime.h>
#include <hip/hip_bf16.h>

// Problem constants (B=2, S=2048, D=1024, H=16, DK=DV=64)
#define H_    16
#define S_    2048
#define D_    1024
#define MAXV  1e10f

typedef __attribute__((ext_vector_type(8))) short short8;
typedef __attribute__((ext_vector_type(4))) float f32x4;

__device__ __forceinline__ unsigned short f2bf(float f) {
    union { float f; unsigned u; } x; x.f = f;
    unsigned r = x.u + 0x7fffu + ((x.u >> 16) & 1u);   // RNE
    return (unsigned short)(r >> 16);
}
__device__ __forceinline__ float bf2f(unsigned short h) {
    union { unsigned u; float f; } x; x.u = ((unsigned)h) << 16; return x.f;
}

// ---------------------------------------------------------------------------
// Kernel 0: per-batch compaction scan of v_mask.
//  cmap[b][j]   = compacted position of key j (-1 if masked)
//  Jc[b][c]     = original index of compacted key c (S_ sentinel beyond count)
//  cumi[b][j]   = # unmasked keys <= j   (inclusive)
// ---------------------------------------------------------------------------
__global__ __launch_bounds__(256) void scan_kernel(
        const int* __restrict__ vmask, int* __restrict__ cmap,
        int* __restrict__ Jc, int* __restrict__ cumi) {
    int bb = blockIdx.x;
    const int* vm = vmask + (size_t)bb * S_;
    int t = threadIdx.x, lane = t & 63, wave = t >> 6;
    int j0 = t * 8;
    int loc[8], tot = 0;
#pragma unroll
    for (int e = 0; e < 8; e++) { loc[e] = vm[j0 + e] ? 1 : 0; tot += loc[e]; }
    int pre = tot;
#pragma unroll
    for (int d = 1; d < 64; d <<= 1) {
        int x = __shfl_up(pre, d);
        if (lane >= d) pre += x;
    }
    __shared__ int wtot[4];
    if (lane == 63) wtot[wave] = pre;
    __syncthreads();
    int wbase = 0;
    for (int w = 0; w < wave; w++) wbase += wtot[w];
    int run = wbase + pre - tot;             // exclusive prefix for this thread
    for (int e = 0; e < 8; e++) {
        int j = j0 + e;
        int before = run;
        run += loc[e];
        cumi[(size_t)bb * S_ + j] = run;
        if (loc[e]) {
            cmap[(size_t)bb * S_ + j] = before;
            Jc[(size_t)bb * S_ + before] = j;
        } else {
            cmap[(size_t)bb * S_ + j] = -1;
        }
    }
    int total = wtot[0] + wtot[1] + wtot[2] + wtot[3];
    for (int c = total + t; c < S_; c += 256) Jc[(size_t)bb * S_ + c] = S_;
}

// ---------------------------------------------------------------------------
// Kernel 1: transpose + convert weights: W[k][n] fp32 -> Wt[n][k] bf16
// ---------------------------------------------------------------------------
__global__ __launch_bounds__(256) void wtrans_kernel(
        const float* __restrict__ w0, const float* __restrict__ w1,
        const float* __restrict__ w2, unsigned short* __restrict__ wt) {
    const float* W = blockIdx.z == 0 ? w0 : (blockIdx.z == 1 ? w1 : w2);
    unsigned short* Wt = wt + (size_t)blockIdx.z * (D_ * D_);
    __shared__ float tile[32][33];
    int t = threadIdx.x;
    int k0 = blockIdx.y * 32, n0 = blockIdx.x * 32;
    int r = t >> 3, c4 = (t & 7) * 4;
    float4 v = *(const float4*)&W[(size_t)(k0 + r) * D_ + n0 + c4];
    tile[r][c4 + 0] = v.x; tile[r][c4 + 1] = v.y;
    tile[r][c4 + 2] = v.z; tile[r][c4 + 3] = v.w;
    __syncthreads();
    ushort4 o;
    o.x = f2bf(tile[c4 + 0][r]); o.y = f2bf(tile[c4 + 1][r]);
    o.z = f2bf(tile[c4 + 2][r]); o.w = f2bf(tile[c4 + 3][r]);
    *(ushort4*)&Wt[(size_t)(n0 + r) * D_ + k0 + c4] = o;
}

// ---------------------------------------------------------------------------
// Kernel 1b: convert q/k/v fp32 -> bf16 flat (measured good: round 9 vs 10,
// the bf16 staging copy saves ~22us inside proj for ~13us of BW work).
// ---------------------------------------------------------------------------
__global__ __launch_bounds__(256) void conv_kernel(
        const float* __restrict__ q, const float* __restrict__ k,
        const float* __restrict__ v, unsigned short* __restrict__ abf) {
    int z = blockIdx.y;
    const float* src = z == 0 ? q : (z == 1 ? k : v);
    unsigned short* dst = abf + (size_t)z * (4096ull * 1024);
    size_t i = ((size_t)blockIdx.x * 256 + threadIdx.x) * 8;
    float4 f1 = *(const float4*)&src[i];
    float4 f2 = *(const float4*)&src[i + 4];
    short8 o;
    o[0] = (short)f2bf(f1.x); o[1] = (short)f2bf(f1.y);
    o[2] = (short)f2bf(f1.z); o[3] = (short)f2bf(f1.w);
    o[4] = (short)f2bf(f2.x); o[5] = (short)f2bf(f2.y);
    o[6] = (short)f2bf(f2.z); o[7] = (short)f2bf(f2.w);
    *(short8*)&dst[i] = o;
}

// ---------------------------------------------------------------------------
// Kernel 2: projection GEMM, 128x128 tile, BK=64, 4 waves (2x2), pipelined
// (T14). 1-D grid 768 with XCD-CHUNKED swizzle: orig=(fid&7)*96+(fid>>3)
// gives each XCD 96 consecutive original ids = 12 A-panels x 8 n-tiles, so
// each 256KB A-panel is fetched into ONE XCD's L2 and reused by its 8
// n-blocks (vs round-robin scattering them across all 8 XCDs).
// PRE=true: A pre-converted bf16. PRE=false: fp32+cvt at ds_write.
// z=0 -> Qh[b][h][s][dk]
// z=1 -> Kc[b][h][c][dk]  (compacted rows via cmap; masked rows dropped)
// z=2 -> Vtc[b][h][dv][c] (compacted transposed)
// ---------------------------------------------------------------------------
template <bool PRE>
__global__ __launch_bounds__(256) void proj_kernel(
        const float* __restrict__ q, const float* __restrict__ k,
        const float* __restrict__ v, const unsigned short* __restrict__ abf,
        const unsigned short* __restrict__ wt, const int* __restrict__ cmap,
        unsigned short* __restrict__ Qh, unsigned short* __restrict__ Kc,
        unsigned short* __restrict__ Vtc) {
    int fid = blockIdx.x;                    // 0..767
    int orig = (fid & 7) * 96 + (fid >> 3);  // bijective chunked XCD swizzle
    int z = orig >> 8;                       // 0..2
    int rem = orig & 255;
    int m0 = (rem >> 3) * 128;               // 32 m-panels
    int n0 = (rem & 7) * 128;                // 8 n-panels
    const float* Af = z == 0 ? q : (z == 1 ? k : v);
    const unsigned short* Ab = abf + (size_t)z * (4096ull * 1024);
    const unsigned short* Bt = wt + (size_t)z * (D_ * D_);
    __shared__ __align__(16) unsigned short As[128][72];   // 144B stride
    __shared__ __align__(16) unsigned short Bs[128][72];
    int t = threadIdx.x;
    int wave = t >> 6, lane = t & 63, lg = lane >> 4, lr = lane & 15;
    int wr = (wave >> 1) * 64, wc = (wave & 1) * 64;
    f32x4 acc[4][4];
#pragma unroll
    for (int mi = 0; mi < 4; mi++)
#pragma unroll
        for (int ni = 0; ni < 4; ni++) acc[mi][ni] = (f32x4){0.f, 0.f, 0.f, 0.f};

    int srow = t >> 3, scol = (t & 7) * 8;   // 32 rows/pass x 64 cols, 4 passes
    short8 aa[4], bb2[4];
    float4 af_[4][2];
    // prologue: load K-chunk 0 into regs
#pragma unroll
    for (int i = 0; i < 4; i++) {
        int row = i * 32 + srow;
        if (PRE) {
            aa[i] = *(const short8*)&Ab[(size_t)(m0 + row) * D_ + scol];
        } else {
            af_[i][0] = *(const float4*)&Af[(size_t)(m0 + row) * D_ + scol];
            af_[i][1] = *(const float4*)&Af[(size_t)(m0 + row) * D_ + scol + 4];
        }
        bb2[i] = *(const short8*)&Bt[(size_t)(n0 + row) * D_ + scol];
    }
    for (int kt = 0; kt < D_ / 64; ++kt) {
        // write staged regs -> LDS
#pragma unroll
        for (int i = 0; i < 4; i++) {
            int row = i * 32 + srow;
            if (PRE) {
                *(short8*)&As[row][scol] = aa[i];
            } else {
                short8 o;
                o[0] = (short)f2bf(af_[i][0].x); o[1] = (short)f2bf(af_[i][0].y);
                o[2] = (short)f2bf(af_[i][0].z); o[3] = (short)f2bf(af_[i][0].w);
                o[4] = (short)f2bf(af_[i][1].x); o[5] = (short)f2bf(af_[i][1].y);
                o[6] = (short)f2bf(af_[i][1].z); o[7] = (short)f2bf(af_[i][1].w);
                *(short8*)&As[row][scol] = o;
            }
            *(short8*)&Bs[row][scol] = bb2[i];
        }
        __syncthreads();
        // issue loads for chunk kt+1 (latency hides under MFMA below)
        if (kt + 1 < D_ / 64) {
            int kk0 = (kt + 1) * 64;
#pragma unroll
            for (int i = 0; i < 4; i++) {
                int row = i * 32 + srow;
                if (PRE) {
                    aa[i] = *(const short8*)&Ab[(size_t)(m0 + row) * D_ + kk0 + scol];
                } else {
                    af_[i][0] = *(const float4*)&Af[(size_t)(m0 + row) * D_ + kk0 + scol];
                    af_[i][1] = *(const float4*)&Af[(size_t)(m0 + row) * D_ + kk0 + scol + 4];
                }
                bb2[i] = *(const short8*)&Bt[(size_t)(n0 + row) * D_ + kk0 + scol];
            }
        }
        short8 af[4][2], bq[4][2];
#pragma unroll
        for (int mi = 0; mi < 4; mi++)
#pragma unroll
            for (int kh = 0; kh < 2; kh++)
                af[mi][kh] = *(const short8*)&As[wr + mi * 16 + lr][kh * 32 + lg * 8];
#pragma unroll
        for (int ni = 0; ni < 4; ni++)
#pragma unroll
            for (int kh = 0; kh < 2; kh++)
                bq[ni][kh] = *(const short8*)&Bs[wc + ni * 16 + lr][kh * 32 + lg * 8];
        __builtin_amdgcn_s_setprio(1);
#pragma unroll
        for (int kh = 0; kh < 2; kh++)
#pragma unroll
            for (int mi = 0; mi < 4; mi++)
#pragma unroll
                for (int ni = 0; ni < 4; ni++)
                    acc[mi][ni] = __builtin_amdgcn_mfma_f32_16x16x32_bf16(
                        af[mi][kh], bq[ni][kh], acc[mi][ni], 0, 0, 0);
        __builtin_amdgcn_s_setprio(0);
        __syncthreads();
    }
    // epilogue: C/D layout row=(lane>>4)*4+rr (m), col=lane&15 (n)
    if (z == 0) {
#pragma unroll
        for (int mi = 0; mi < 4; mi++) {
#pragma unroll
            for (int ni = 0; ni < 4; ni++) {
                int col = n0 + wc + ni * 16 + lr;
                int hh = col >> 6, dk = col & 63;
#pragma unroll
                for (int rr = 0; rr < 4; rr++) {
                    int m = m0 + wr + mi * 16 + lg * 4 + rr;
                    int bb = m >> 11, s = m & (S_ - 1);
                    Qh[(((size_t)(bb * H_ + hh)) * S_ + s) * 64 + dk] =
                        f2bf(acc[mi][ni][rr]);
                }
            }
        }
    } else {
        int cm_[4][4], bb_[4][4];
#pragma unroll
        for (int mi = 0; mi < 4; mi++)
#pragma unroll
            for (int rr = 0; rr < 4; rr++) {
                int m = m0 + wr + mi * 16 + lg * 4 + rr;
                int bb = m >> 11, s = m & (S_ - 1);
                bb_[mi][rr] = bb;
                cm_[mi][rr] = cmap[(size_t)bb * S_ + s];
            }
#pragma unroll
        for (int mi = 0; mi < 4; mi++) {
#pragma unroll
            for (int ni = 0; ni < 4; ni++) {
                int col = n0 + wc + ni * 16 + lr;
                int hh = col >> 6, dd = col & 63;
#pragma unroll
                for (int rr = 0; rr < 4; rr++) {
                    int c = cm_[mi][rr];
                    if (c < 0) continue;
                    int bb = bb_[mi][rr];
                    if (z == 1)
                        Kc[(((size_t)(bb * H_ + hh)) * S_ + c) * 64 + dd] =
                            f2bf(acc[mi][ni][rr]);
                    else
                        Vtc[(((size_t)(bb * H_ + hh)) * 64 + dd) * S_ + c] =
                            f2bf(acc[mi][ni][rr]);
                }
            }
        }
    }
}

// ---------------------------------------------------------------------------
// Kernel 3: causal flash attention over COMPACTED keys (round-9 version,
// QBLK=64 — measured best). 1-D grid 1024, XCD-swizzled LPT decode:
// xcd = fid&7 keeps each (h,b) group's K/V on one XCD's L2; qt = 31-(slot>>2)
// dispatches HEAVY q-tiles first so light blocks backfill the tail.
// One q-tile (64 rows) per block, 4 waves; tile t+1 loads issue before
// compute of tile t (T14).
// ---------------------------------------------------------------------------
__global__ __launch_bounds__(256) void attn_kernel(
        const unsigned short* __restrict__ Qh, const unsigned short* __restrict__ Kc,
        const unsigned short* __restrict__ Vtc, const int* __restrict__ Jc,
        const int* __restrict__ cumi, const int* __restrict__ qmask,
        float* __restrict__ out) {
    int fid = blockIdx.x;                   // 0..1023
    int xcd = fid & 7, slot = fid >> 3;     // slot 0..127
    int qt = 31 - (slot >> 2);              // heavy (large qt) first
    int g = xcd + 8 * (slot & 3);           // 0..31 = h + 16*b
    int hh = g & 15, bb = g >> 4;
    const unsigned short* Qp = Qh + ((size_t)(bb * H_ + hh)) * S_ * 64;
    const unsigned short* Kp = Kc + ((size_t)(bb * H_ + hh)) * S_ * 64;
    const unsigned short* Vp = Vtc + ((size_t)(bb * H_ + hh)) * 64 * S_;
    const int* Jb = Jc + (size_t)bb * S_;
    int t = threadIdx.x, wave = t >> 6, lane = t & 63, lg = lane >> 4, lr = lane & 15;
    __shared__ __align__(16) unsigned short Ks[64 * 64];
    __shared__ __align__(16) unsigned short Vs[64 * 64];
    __shared__ __align__(16) unsigned short Pl[4][16][72];  // 144B stride

    int q0 = qt * 64 + wave * 16;
    int nc = cumi[(size_t)bb * S_ + qt * 64 + 63];
    int nt = (nc + 63) >> 6;
    short8 qf[2];
#pragma unroll
    for (int kh = 0; kh < 2; kh++)
        qf[kh] = *(const short8*)&Qp[(size_t)(q0 + lr) * 64 + kh * 32 + lg * 8];
    f32x4 oacc[4];
#pragma unroll
    for (int ni = 0; ni < 4; ni++) oacc[ni] = (f32x4){0.f, 0.f, 0.f, 0.f};
    float m_run[4], l_run[4];
    int qrow[4];
#pragma unroll
    for (int rr = 0; rr < 4; rr++) {
        m_run[rr] = -__builtin_inff(); l_run[rr] = 0.f;
        qrow[rr] = q0 + lg * 4 + rr;
    }
    // per-thread staging geometry (2 passes x 16B)
    int soff[2], srw[2], scsw[2];
#pragma unroll
    for (int i = 0; i < 2; i++) {
        soff[i] = i * 4096 + t * 16;
        srw[i] = soff[i] >> 7;
        scsw[i] = (soff[i] & 127) ^ ((srw[i] & 7) << 4);
    }
    short8 kreg[2], vreg[2];
    if (nt > 0) {
#pragma unroll
        for (int i = 0; i < 2; i++) {
            kreg[i] = *(const short8*)((const char*)Kp + (size_t)srw[i] * 128 + scsw[i]);
            vreg[i] = *(const short8*)((const char*)Vp + (size_t)srw[i] * 4096 + scsw[i]);
        }
    }

    for (int kt = 0; kt < nt; ++kt) {
        int kv0 = kt * 64;
        // write staged regs -> LDS (swizzled layout)
#pragma unroll
        for (int i = 0; i < 2; i++) {
            *(short8*)((char*)Ks + soff[i]) = kreg[i];
            *(short8*)((char*)Vs + soff[i]) = vreg[i];
        }
        __syncthreads();
        // issue next tile's loads; latency hides under QK/softmax/PV
        if (kt + 1 < nt) {
            int kv0n = (kt + 1) * 64;
#pragma unroll
            for (int i = 0; i < 2; i++) {
                kreg[i] = *(const short8*)((const char*)Kp + (size_t)(kv0n + srw[i]) * 128 + scsw[i]);
                vreg[i] = *(const short8*)((const char*)Vp + (size_t)srw[i] * 4096 + kv0n * 2 + scsw[i]);
            }
        }
        f32x4 sacc[4];
#pragma unroll
        for (int ni = 0; ni < 4; ni++) sacc[ni] = (f32x4){0.f, 0.f, 0.f, 0.f};
        __builtin_amdgcn_s_setprio(1);
#pragma unroll
        for (int ni = 0; ni < 4; ni++) {
            int row = ni * 16 + lr;
#pragma unroll
            for (int kh = 0; kh < 2; kh++) {
                int cb = (kh * 64 + lg * 16) ^ ((row & 7) << 4);
                short8 kf = *(const short8*)((const char*)Ks + row * 128 + cb);
                sacc[ni] = __builtin_amdgcn_mfma_f32_16x16x32_bf16(qf[kh], kf, sacc[ni], 0, 0, 0);
            }
        }
        __builtin_amdgcn_s_setprio(0);
        // scale + causal mask on ORIGINAL index (sentinel S_ for pad)
        float sv[4][4];
#pragma unroll
        for (int ni = 0; ni < 4; ni++) {
            int jo = Jb[kv0 + ni * 16 + lr];
#pragma unroll
            for (int rr = 0; rr < 4; rr++) {
                float s = sacc[ni][rr] * 0.125f;
                if (jo > qrow[rr]) s -= MAXV;
                sv[ni][rr] = s;
            }
        }
        float scl[4];
#pragma unroll
        for (int rr = 0; rr < 4; rr++) {
            float a = fmaxf(fmaxf(sv[0][rr], sv[1][rr]), fmaxf(sv[2][rr], sv[3][rr]));
#pragma unroll
            for (int d = 1; d < 16; d <<= 1) a = fmaxf(a, __shfl_xor(a, d));
            float mn = fmaxf(m_run[rr], a);
            scl[rr] = __expf(m_run[rr] - mn);
            m_run[rr] = mn;
        }
        float pw[4][4], ps[4];
#pragma unroll
        for (int rr = 0; rr < 4; rr++) ps[rr] = 0.f;
#pragma unroll
        for (int ni = 0; ni < 4; ni++)
#pragma unroll
            for (int rr = 0; rr < 4; rr++) {
                pw[ni][rr] = __expf(sv[ni][rr] - m_run[rr]);
                ps[rr] += pw[ni][rr];
            }
#pragma unroll
        for (int rr = 0; rr < 4; rr++) {
#pragma unroll
            for (int d = 1; d < 16; d <<= 1) ps[rr] += __shfl_xor(ps[rr], d);
            l_run[rr] = l_run[rr] * scl[rr] + ps[rr];
        }
#pragma unroll
        for (int ni = 0; ni < 4; ni++)
#pragma unroll
            for (int rr = 0; rr < 4; rr++) oacc[ni][rr] *= scl[rr];
#pragma unroll
        for (int ni = 0; ni < 4; ni++)
#pragma unroll
            for (int rr = 0; rr < 4; rr++)
                Pl[wave][lg * 4 + rr][ni * 16 + lr] = f2bf(pw[ni][rr]);
        short8 pa[2];
#pragma unroll
        for (int kh = 0; kh < 2; kh++)
            pa[kh] = *(const short8*)&Pl[wave][lr][kh * 32 + lg * 8];
        __builtin_amdgcn_s_setprio(1);
#pragma unroll
        for (int ni = 0; ni < 4; ni++) {
            int rowd = ni * 16 + lr;
#pragma unroll
            for (int kh = 0; kh < 2; kh++) {
                int cb = (kh * 64 + lg * 16) ^ ((rowd & 7) << 4);
                short8 vf = *(const short8*)((const char*)Vs + rowd * 128 + cb);
                oacc[ni] = __builtin_amdgcn_mfma_f32_16x16x32_bf16(pa[kh], vf, oacc[ni], 0, 0, 0);
            }
        }
        __builtin_amdgcn_s_setprio(0);
        __syncthreads();
    }
    // epilogue
#pragma unroll
    for (int rr = 0; rr < 4; rr++) {
        int qm = qmask[bb * S_ + qrow[rr]];
        float f = (qm != 0 && l_run[rr] > 0.f) ? (float)qm / l_run[rr] : 0.f;
#pragma unroll
        for (int ni = 0; ni < 4; ni++)
            out[((size_t)(bb * S_ + qrow[rr])) * D_ + hh * 64 + ni * 16 + lr] =
                oacc[ni][rr] * f;
    }
}

// ---------------------------------------------------------------------------
// Kernel 4: degenerate-row fixup (rows r < d = first unmasked key).
// out[r][p] = (sum_{j<=r} vh[j][p] + sum_all_compacted vh[.][p]) / (r+1+ccount)
// prefix vh recomputed from v . Wt (masked rows are not in compacted V).
// ---------------------------------------------------------------------------
__global__ __launch_bounds__(256) void fixup_kernel(
        const int* __restrict__ qmask, const float* __restrict__ v,
        const unsigned short* __restrict__ wt, const unsigned short* __restrict__ Vtc,
        const int* __restrict__ Jc, const int* __restrict__ cumi,
        float* __restrict__ out) {
    int bb = blockIdx.y;
    int p0 = blockIdx.x * 16;
    int t = threadIdx.x;
    int pl = t >> 4, jl = t & 15;
    int d = Jc[(size_t)bb * S_];                 // first unmasked key (S_ if none)
    if (d == 0) return;
    int ccount = cumi[(size_t)bb * S_ + S_ - 1];
    int p = p0 + pl;
    int hh = p >> 6, dv = p & 63;
    const unsigned short* vrow = Vtc + ((size_t)(bb * H_ + hh) * 64 + dv) * S_;
    float suf = 0.f;
    for (int c = jl; c < ccount; c += 16) suf += bf2f(vrow[c]);
#pragma unroll
    for (int dd = 1; dd < 16; dd <<= 1) suf += __shfl_xor(suf, dd);
    // prefix rows on the fly: vh[r][p] = v[b][r][:] . Wv[:][p] (bf16 weights)
    const unsigned short* wcol = wt + 2ull * D_ * D_ + (size_t)p * D_;  // Wv^T row p
    float pre = 0.f;
    for (int r = 0; r < d; ++r) {
        const float* vr = v + ((size_t)bb * S_ + r) * D_;
        float acc = 0.f;
        for (int kk = jl * 64; kk < jl * 64 + 64; kk += 8) {
            float4 a1 = *(const float4*)&vr[kk];
            float4 a2 = *(const float4*)&vr[kk + 4];
            acc += a1.x * bf2f(wcol[kk + 0]) + a1.y * bf2f(wcol[kk + 1]) +
                   a1.z * bf2f(wcol[kk + 2]) + a1.w * bf2f(wcol[kk + 3]) +
                   a2.x * bf2f(wcol[kk + 4]) + a2.y * bf2f(wcol[kk + 5]) +
                   a2.z * bf2f(wcol[kk + 6]) + a2.w * bf2f(wcol[kk + 7]);
        }
#pragma unroll
        for (int dd = 1; dd < 16; dd <<= 1) acc += __shfl_xor(acc, dd);
        pre += acc;
        if (jl == 0 && qmask[(size_t)bb * S_ + r] != 0)
            out[((size_t)(bb * S_ + r)) * D_ + p] =
                (pre + suf) / (float)(r + 1 + ccount);
    }
}

// ---------------------------------------------------------------------------
extern "C" void kernel_launch(void* const* d_in, const int* in_sizes, int n_in,
                              void* d_out, int out_size, void* d_ws, size_t ws_size,
                              hipStream_t stream) {
    const float* q  = (const float*)d_in[0];
    const float* k  = (const float*)d_in[1];
    const float* v  = (const float*)d_in[2];
    const int* vmask = (const int*)d_in[3];
    const int* qmask = (const int*)d_in[4];
    const float* Wq = (const float*)d_in[5];
    const float* Wk = (const float*)d_in[6];
    const float* Wv = (const float*)d_in[7];
    float* out = (float*)d_out;

    char* ws = (char*)d_ws;
    const size_t MB = 1024ull * 1024;
    int* cmap = (int*)ws;                                   // 16 KB
    int* Jc   = (int*)(ws + 16 * 1024);                     // 16 KB
    int* cumi = (int*)(ws + 32 * 1024);                     // 16 KB
    unsigned short* Wt  = (unsigned short*)(ws + 64 * 1024);          // 6 MB
    unsigned short* Qh  = (unsigned short*)(ws + 64 * 1024 + 6 * MB); // 8 MB
    unsigned short* Kc  = (unsigned short*)(ws + 64 * 1024 + 14 * MB);// 8 MB
    unsigned short* Vtc = (unsigned short*)(ws + 64 * 1024 + 22 * MB);// 8 MB
    unsigned short* Abf = (unsigned short*)(ws + 64 * 1024 + 30 * MB);// 24 MB
    bool pre = ws_size >= 64 * 1024 + 54 * MB;

    scan_kernel<<<dim3(2), 256, 0, stream>>>(vmask, cmap, Jc, cumi);
    wtrans_kernel<<<dim3(32, 32, 3), 256, 0, stream>>>(Wq, Wk, Wv, Wt);
    if (pre) {
        conv_kernel<<<dim3(2048, 3), 256, 0, stream>>>(q, k, v, Abf);
        proj_kernel<true><<<dim3(768), 256, 0, stream>>>(
            q, k, v, Abf, Wt, cmap, Qh, Kc, Vtc);
    } else {
        proj_kernel<false><<<dim3(768), 256, 0, stream>>>(
            q, k, v, Abf, Wt, cmap, Qh, Kc, Vtc);
    }
    attn_kernel<<<dim3(1024), 256, 0, stream>>>(Qh, Kc, Vtc, Jc, cumi, qmask, out);
    fixup_kernel<<<dim3(64, 2), 256, 0, stream>>>(qmask, v, Wt, Vtc, Jc, cumi, out);
}